// Round 2
// baseline (457.842 us; speedup 1.0000x reference)
//
#include <hip/hip_runtime.h>
#include <math.h>

#define BETA 0.9f
#define THR  1.0f
#define LEAK 0.9f
#define BB   32
#define DIN  1024
#define DOUT 1024

// d_out flat layout (return order): s, E_W2, E_b2, Rh_W2, Rh_b2, g_bar2, r2
#define OFF_S    0
#define OFF_EW   (BB*DOUT)                         // 32768
#define OFF_EB   (OFF_EW + BB*DIN*DOUT)            // 33587200
#define OFF_RHW  (OFF_EB + BB*DOUT)                // 33619968
#define OFF_RHB  (OFF_RHW + BB*DIN*DOUT)           // 67174400
#define OFF_GBAR (OFF_RHB + BB*DOUT)               // 67207168
#define OFF_R2   (OFF_GBAR + BB*DOUT)              // 67239936

typedef float v4f __attribute__((ext_vector_type(4)));
typedef float v2f __attribute__((ext_vector_type(2)));

// Kernel 1: h = x@W + b, then all per-(b,o) pointwise outputs.
// grid = (DOUT/128, B) = (8, 32) -> 256 blocks, one per CU.
// block = 256 (4 waves; each wave owns a K-quarter, 128 output cols,
// float2 per lane). Per-block W stream: 512 KB (was 1 MB).
__global__ __launch_bounds__(256) void k1_matmul_pointwise(
    const float* __restrict__ x, const float* __restrict__ W,
    const float* __restrict__ bias, const float* __restrict__ u,
    const float* __restrict__ E_b, const float* __restrict__ Rh_b,
    const float* __restrict__ g_bar, const float* __restrict__ r,
    float* __restrict__ out)
{
    const int batch = blockIdx.y;
    const int obase = blockIdx.x * 128;
    const int t    = threadIdx.x;
    const int lane = t & 63;      // column pair within the 128-wide strip
    const int kc   = t >> 6;      // wave id = K-quarter 0..3

    const float* xrow = x + batch * DIN;      // uniform per wave -> s_loads
    const int k0 = kc * (DIN / 4);
    const float* wp = W + (size_t)k0 * DOUT + obase + lane * 2;

    v2f acc = 0.f;
    #pragma unroll 8
    for (int j = 0; j < DIN / 4; ++j) {
        const float xk = xrow[k0 + j];
        const v2f  w2 = *(const v2f*)wp;
        acc.x = fmaf(xk, w2.x, acc.x);
        acc.y = fmaf(xk, w2.y, acc.y);
        wp += DOUT;
    }

    __shared__ v2f red[4][64];
    red[kc][lane] = acc;
    __syncthreads();

    if (t < 64) {
        const v2f a = red[0][lane], b2 = red[1][lane],
                  c2 = red[2][lane], d2 = red[3][lane];
        const int idx  = batch * DOUT + obase + lane * 2;   // 8B-aligned
        const int oidx = obase + lane * 2;

        const v2f bb = *(const v2f*)(bias + oidx);
        const v2f uu = *(const v2f*)(u     + idx);
        const v2f eb = *(const v2f*)(E_b   + idx);
        const v2f rh = *(const v2f*)(Rh_b  + idx);
        const v2f gb = *(const v2f*)(g_bar + idx);

        const float rb    = r[batch];
        const float r2    = fmaf(LEAK, rb, 1.f);
        const float ratio = (LEAK * rb) / r2;

        v2f h2;
        h2.x = a.x + b2.x + c2.x + d2.x + bb.x;
        h2.y = a.y + b2.y + c2.y + d2.y + bb.y;

        v2f s2, eb2, rhb2, gb2;
        #pragma unroll
        for (int c = 0; c < 2; ++c) {
            const float un   = fmaf(BETA, uu[c], h2[c]);
            const float s    = 1.f / (1.f + expf(-(un - THR)));
            const float sg   = s * (1.f - s);
            const float dsdu = BETA * sg;

            const float eb1  = fmaf(BETA, eb[c], 1.f);
            const float dthb = fmaf(dsdu, eb1, sg);

            s2[c]   = s;
            eb2[c]  = fmaf(BETA, eb1, 1.f);
            rhb2[c] = fmaf(dsdu, rh[c], dthb);
            gb2[c]  = fmaf(ratio, gb[c], (1.f - ratio) * dsdu);
        }

        *(v2f*)(out + OFF_S    + idx) = s2;
        *(v2f*)(out + OFF_EB   + idx) = eb2;
        *(v2f*)(out + OFF_RHB  + idx) = rhb2;
        *(v2f*)(out + OFF_GBAR + idx) = gb2;
        if (blockIdx.x == 0 && t == 0) out[OFF_R2 + batch] = r2;
    }
}

// Kernel 2: the 32M-element trace update over (B, DIN, DOUT).
// grid = BB * DIN/8 = 4096 blocks; each block owns 8 consecutive rows of ONE
// batch, so the s-row (and derived sg/dsdu) is loaded once and reused 8x.
// block = 256 threads, float4/thread/row. Touch-once streams use nontemporal.
#define ROWS_PER_BLK 8
__global__ __launch_bounds__(256) void k2_traces(
    const float* __restrict__ x, const float* __restrict__ E_W,
    const float* __restrict__ Rh_W, float* __restrict__ out)
{
    const int batch = blockIdx.x >> 7;            // 128 row-groups per batch
    const int rgrp  = blockIdx.x & 127;
    const long long row0 = (long long)batch * DIN + rgrp * ROWS_PER_BLK;
    const int t = threadIdx.x;

    // s row is shared by all 8 rows of this block: load once, derive once.
    const v4f s4 = ((const v4f*)(out + OFF_S + (long long)batch * DOUT))[t];
    v4f sgv, dsduv;
    #pragma unroll
    for (int c = 0; c < 4; ++c) {
        sgv[c]   = s4[c] * (1.f - s4[c]);
        dsduv[c] = BETA * sgv[c];
    }

    #pragma unroll
    for (int jr = 0; jr < ROWS_PER_BLK; ++jr) {
        const long long row  = row0 + jr;
        const long long roff = row * DOUT;
        const float xv = x[row];

        const v4f ew = __builtin_nontemporal_load((const v4f*)(E_W  + roff) + t);
        const v4f rh = __builtin_nontemporal_load((const v4f*)(Rh_W + roff) + t);

        v4f ew2, rh2;
        #pragma unroll
        for (int c = 0; c < 4; ++c) {
            const float e1  = fmaf(BETA, ew[c], xv);
            const float dth = fmaf(dsduv[c], e1, xv * sgv[c]);
            ew2[c] = fmaf(BETA, e1, xv);
            rh2[c] = fmaf(dsduv[c], rh[c], dth);
        }

        __builtin_nontemporal_store(ew2, (v4f*)(out + OFF_EW  + roff) + t);
        __builtin_nontemporal_store(rh2, (v4f*)(out + OFF_RHW + roff) + t);
    }
}

extern "C" void kernel_launch(void* const* d_in, const int* in_sizes, int n_in,
                              void* d_out, int out_size, void* d_ws, size_t ws_size,
                              hipStream_t stream) {
    const float* x     = (const float*)d_in[0];
    const float* W     = (const float*)d_in[1];
    const float* bias  = (const float*)d_in[2];
    const float* u     = (const float*)d_in[3];
    const float* E_W   = (const float*)d_in[4];
    const float* E_b   = (const float*)d_in[5];
    const float* Rh_W  = (const float*)d_in[6];
    const float* Rh_b  = (const float*)d_in[7];
    const float* g_bar = (const float*)d_in[8];
    const float* r     = (const float*)d_in[9];
    float* out = (float*)d_out;

    dim3 g1(DOUT / 128, BB);
    k1_matmul_pointwise<<<g1, 256, 0, stream>>>(x, W, bias, u, E_b, Rh_b, g_bar, r, out);
    k2_traces<<<BB * (DIN / ROWS_PER_BLK), 256, 0, stream>>>(x, E_W, Rh_W, out);
}